// Round 5
// baseline (304.968 us; speedup 1.0000x reference)
//
#include <hip/hip_runtime.h>
#include <math.h>

#define NPG 500      // nodes per graph
#define DIM 256      // feature dim
#define HID 64       // hidden dim
#define RATIO_NORM 600.0f
#define WPB 4        // waves per block in k_score
#define HPW (HID / WPB)   // 16 hidden units per wave

// One k4-tile of this wave's weight slice: 4 k-rows x 16 h = 64 floats.
struct WT { float4 w[16]; };

__device__ __forceinline__ void load_tile(const float* base, WT& t) {
    // base = Ws1 + (k4*4)*HID + h0 ; rows stride HID floats.
    // Address is wave-uniform in VALUE but not provably uniform to the
    // compiler (no readfirstlane) -> per-lane vector loads, HW-coalesced
    // broadcast. This keeps weights OFF the scalar path (vmcnt pipelining).
#pragma unroll
    for (int kk = 0; kk < 4; ++kk)
#pragma unroll
        for (int j = 0; j < 4; ++j)
            t.w[kk * 4 + j] =
                *reinterpret_cast<const float4*>(base + kk * HID + j * 4);
}

__device__ __forceinline__ void fma4(float xk0, float xk1, const float4* w,
                                     float4* A, float4* B) {
#pragma unroll
    for (int j = 0; j < 4; ++j) {
        A[j].x = fmaf(xk0, w[j].x, A[j].x);  B[j].x = fmaf(xk1, w[j].x, B[j].x);
        A[j].y = fmaf(xk0, w[j].y, A[j].y);  B[j].y = fmaf(xk1, w[j].y, B[j].y);
        A[j].z = fmaf(xk0, w[j].z, A[j].z);  B[j].z = fmaf(xk1, w[j].z, B[j].z);
        A[j].w = fmaf(xk0, w[j].w, A[j].w);  B[j].w = fmaf(xk1, w[j].w, B[j].w);
    }
}

__device__ __forceinline__ void fma_tile(const WT& t, float4 xa, float4 xb,
                                         float4* A, float4* B) {
    fma4(xa.x, xb.x, t.w + 0,  A, B);
    fma4(xa.y, xb.y, t.w + 4,  A, B);
    fma4(xa.z, xb.z, t.w + 8,  A, B);
    fma4(xa.w, xb.w, t.w + 12, A, B);
}

// ---------------------------------------------------------------- K1: scores
// score[n] = relu(x[n,:] @ Ws1 + bs1) @ Ws2 + bs2
// lane = node (2 per lane), wave = 16-wide h-slice. Weights double-buffered
// in VGPRs via vector loads (1 tile ahead); x 3-deep prefetch (L3 ~700cy).
__global__ __launch_bounds__(256, 2) void k_score(
    const float* __restrict__ x,
    const float* __restrict__ Ws1,   // [DIM][HID] row-major
    const float* __restrict__ bs1,   // [HID]
    const float* __restrict__ Ws2,   // [HID]
    const float* __restrict__ bs2,   // [1]
    float* __restrict__ score, int N)
{
    int lane = threadIdx.x & 63;
    int wv   = threadIdx.x >> 6;
    int h0   = wv * HPW;
    int base = blockIdx.x * 128;
    int n0 = base + lane;
    int n1 = base + 64 + lane;
    int n0c = n0 < N ? n0 : (N - 1);
    int n1c = n1 < N ? n1 : (N - 1);

    const float4* xr0 = reinterpret_cast<const float4*>(x + (size_t)n0c * DIM);
    const float4* xr1 = reinterpret_cast<const float4*>(x + (size_t)n1c * DIM);
    const float* bs = bs1 + h0;

    float4 A[4], B[4];
#pragma unroll
    for (int j = 0; j < 4; ++j) {
        A[j] = *reinterpret_cast<const float4*>(bs + j * 4);
        B[j] = A[j];
    }

    WT wA, wB;
    load_tile(Ws1 + h0, wA);                       // tile 0
    float4 xa0 = xr0[0], xa1 = xr0[1], xa2 = xr0[2];
    float4 xb0 = xr1[0], xb1 = xr1[1], xb2 = xr1[2];

    for (int k4 = 0; k4 < DIM / 4; k4 += 2) {
        // even half: prefetch tile k4+1, compute tile k4
        load_tile(Ws1 + (size_t)(k4 + 1) * 4 * HID + h0, wB);
        fma_tile(wA, xa0, xb0, A, B);
        {
            int ix = k4 + 3 < DIM / 4 ? k4 + 3 : DIM / 4 - 1;
            xa0 = xa1; xa1 = xa2; xa2 = xr0[ix];
            xb0 = xb1; xb1 = xb2; xb2 = xr1[ix];
        }
        // odd half: prefetch tile k4+2, compute tile k4+1
        if (k4 + 2 < DIM / 4)
            load_tile(Ws1 + (size_t)(k4 + 2) * 4 * HID + h0, wA);
        fma_tile(wB, xa0, xb0, A, B);
        {
            int ix = k4 + 4 < DIM / 4 ? k4 + 4 : DIM / 4 - 1;
            xa0 = xa1; xa1 = xa2; xa2 = xr0[ix];
            xb0 = xb1; xb1 = xb2; xb2 = xr1[ix];
        }
    }

    // second layer partial on this wave's 16 h
    float4 w20 = *reinterpret_cast<const float4*>(Ws2 + h0);
    float4 w21 = *reinterpret_cast<const float4*>(Ws2 + h0 + 4);
    float4 w22 = *reinterpret_cast<const float4*>(Ws2 + h0 + 8);
    float4 w23 = *reinterpret_cast<const float4*>(Ws2 + h0 + 12);
    float p0 = 0.0f, p1 = 0.0f;
    p0 = fmaf(fmaxf(A[0].x, 0.0f), w20.x, p0);  p1 = fmaf(fmaxf(B[0].x, 0.0f), w20.x, p1);
    p0 = fmaf(fmaxf(A[0].y, 0.0f), w20.y, p0);  p1 = fmaf(fmaxf(B[0].y, 0.0f), w20.y, p1);
    p0 = fmaf(fmaxf(A[0].z, 0.0f), w20.z, p0);  p1 = fmaf(fmaxf(B[0].z, 0.0f), w20.z, p1);
    p0 = fmaf(fmaxf(A[0].w, 0.0f), w20.w, p0);  p1 = fmaf(fmaxf(B[0].w, 0.0f), w20.w, p1);
    p0 = fmaf(fmaxf(A[1].x, 0.0f), w21.x, p0);  p1 = fmaf(fmaxf(B[1].x, 0.0f), w21.x, p1);
    p0 = fmaf(fmaxf(A[1].y, 0.0f), w21.y, p0);  p1 = fmaf(fmaxf(B[1].y, 0.0f), w21.y, p1);
    p0 = fmaf(fmaxf(A[1].z, 0.0f), w21.z, p0);  p1 = fmaf(fmaxf(B[1].z, 0.0f), w21.z, p1);
    p0 = fmaf(fmaxf(A[1].w, 0.0f), w21.w, p0);  p1 = fmaf(fmaxf(B[1].w, 0.0f), w21.w, p1);
    p0 = fmaf(fmaxf(A[2].x, 0.0f), w22.x, p0);  p1 = fmaf(fmaxf(B[2].x, 0.0f), w22.x, p1);
    p0 = fmaf(fmaxf(A[2].y, 0.0f), w22.y, p0);  p1 = fmaf(fmaxf(B[2].y, 0.0f), w22.y, p1);
    p0 = fmaf(fmaxf(A[2].z, 0.0f), w22.z, p0);  p1 = fmaf(fmaxf(B[2].z, 0.0f), w22.z, p1);
    p0 = fmaf(fmaxf(A[2].w, 0.0f), w22.w, p0);  p1 = fmaf(fmaxf(B[2].w, 0.0f), w22.w, p1);
    p0 = fmaf(fmaxf(A[3].x, 0.0f), w23.x, p0);  p1 = fmaf(fmaxf(B[3].x, 0.0f), w23.x, p1);
    p0 = fmaf(fmaxf(A[3].y, 0.0f), w23.y, p0);  p1 = fmaf(fmaxf(B[3].y, 0.0f), w23.y, p1);
    p0 = fmaf(fmaxf(A[3].z, 0.0f), w23.z, p0);  p1 = fmaf(fmaxf(B[3].z, 0.0f), w23.z, p1);
    p0 = fmaf(fmaxf(A[3].w, 0.0f), w23.w, p0);  p1 = fmaf(fmaxf(B[3].w, 0.0f), w23.w, p1);

    __shared__ float part[WPB][128];
    part[wv][lane] = p0;
    part[wv][64 + lane] = p1;
    __syncthreads();
    if (wv == 0) {
        float s0 = part[0][lane] + part[1][lane] + part[2][lane] + part[3][lane]
                 + bs2[0];
        float s1 = part[0][64 + lane] + part[1][64 + lane] + part[2][64 + lane]
                 + part[3][64 + lane] + bs2[0];
        if (n0 < N) score[n0] = s0;
        if (n1 < N) score[n1] = s1;
    }
}

// ------------------------------------------------------------- K2: edge count
__global__ __launch_bounds__(256) void k_edges(
    const int* __restrict__ esrc, const int* __restrict__ edst,
    int* __restrict__ counts, int E, int G)
{
    __shared__ int hist[256];
    for (int i = threadIdx.x; i < G; i += 256) hist[i] = 0;
    __syncthreads();

    int nchunk = E >> 2;
    const int4* s4 = reinterpret_cast<const int4*>(esrc);
    const int4* d4 = reinterpret_cast<const int4*>(edst);
    for (int c = blockIdx.x * 256 + threadIdx.x; c < nchunk; c += gridDim.x * 256) {
        int4 s = s4[c], d = d4[c];
        int g;
        g = s.x / NPG; if (g == d.x / NPG) atomicAdd(&hist[g], 1);
        g = s.y / NPG; if (g == d.y / NPG) atomicAdd(&hist[g], 1);
        g = s.z / NPG; if (g == d.z / NPG) atomicAdd(&hist[g], 1);
        g = s.w / NPG; if (g == d.w / NPG) atomicAdd(&hist[g], 1);
    }
    if (blockIdx.x == 0) {
        for (int e = (nchunk << 2) + threadIdx.x; e < E; e += 256) {
            int g = esrc[e] / NPG;
            if (g == edst[e] / NPG) atomicAdd(&hist[g], 1);
        }
    }
    __syncthreads();
    for (int i = threadIdx.x; i < G; i += 256)
        if (hist[i]) atomicAdd(&counts[i], hist[i]);
}

// ------------------------------------------- K3: per-graph avg + keep_num MLP
__global__ __launch_bounds__(256) void k_keep(
    const float* __restrict__ score,
    const int* __restrict__ counts,
    const float* __restrict__ Wp1,   // [3][HID]
    const float* __restrict__ bp1,   // [HID]
    const float* __restrict__ Wp2,   // [HID]
    const float* __restrict__ bp2,   // [1]
    int* __restrict__ keep_num)
{
    int g = blockIdx.x;
    __shared__ float red[256];
    const float* s = score + (size_t)g * NPG;
    float v = 0.0f;
    for (int i = threadIdx.x; i < NPG; i += 256) v += s[i];
    red[threadIdx.x] = v;
    __syncthreads();
    for (int off = 128; off >= 1; off >>= 1) {
        if (threadIdx.x < off) red[threadIdx.x] += red[threadIdx.x + off];
        __syncthreads();
    }
    if (threadIdx.x < 64) {
        float f0 = (float)NPG / RATIO_NORM;
        float f1 = red[0] / (float)NPG;
        float f2 = (float)counts[g] / (float)(NPG * (NPG - 1));
        int h = threadIdx.x;
        float hv = bp1[h];
        hv = fmaf(f0, Wp1[h], hv);
        hv = fmaf(f1, Wp1[HID + h], hv);
        hv = fmaf(f2, Wp1[2 * HID + h], hv);
        hv = fmaxf(hv, 0.0f) * Wp2[h];
#pragma unroll
        for (int m = 32; m >= 1; m >>= 1) hv += __shfl_xor(hv, m, 64);
        if (h == 0) {
            float z = hv + bp2[0];
            float kr = 1.0f / (1.0f + expf(-z));
            int kn = (int)((float)NPG * kr);
            keep_num[g] = kn < 2 ? 2 : kn;
        }
    }
}

// ---------------------------- K4a: per-graph rank -> mask (float) + gate tanh
__global__ __launch_bounds__(256) void k_rank(
    const float* __restrict__ score,
    const int* __restrict__ keep_num,
    float* __restrict__ out_mask,   // [N] 0.0/1.0
    float* __restrict__ gate)       // [N] tanh(score) or 0
{
    int g = blockIdx.x;
    __shared__ float s[NPG];
    const float* sg = score + (size_t)g * NPG;
    for (int i = threadIdx.x; i < NPG; i += 256) s[i] = sg[i];
    __syncthreads();

    int kn = keep_num[g];
    for (int i = threadIdx.x; i < NPG; i += 256) {
        float si = s[i];
        int rank = 0;
        for (int j = 0; j < NPG; ++j) {
            float sj = s[j];
            rank += (sj > si) || ((sj == si) && (j < i));
        }
        bool keep = rank < kn;
        size_t idx = (size_t)g * NPG + i;
        out_mask[idx] = keep ? 1.0f : 0.0f;
        gate[idx] = keep ? tanhf(si) : 0.0f;
    }
}

// ------------------------------------------ K4b: gated row write (full BW)
__global__ __launch_bounds__(256) void k_write(
    const float* __restrict__ x,
    const float* __restrict__ gate,
    float* __restrict__ out_x, int N)
{
    int lane = threadIdx.x & 63;
    int row = blockIdx.x * 4 + (threadIdx.x >> 6);
    if (row >= N) return;
    float gt = gate[row];
    size_t base = (size_t)row * DIM;
    float4* o = reinterpret_cast<float4*>(out_x + base);
    if (gt != 0.0f) {
        const float4* xi = reinterpret_cast<const float4*>(x + base);
        float4 v = xi[lane];
        o[lane] = make_float4(v.x * gt, v.y * gt, v.z * gt, v.w * gt);
    } else {
        o[lane] = make_float4(0.0f, 0.0f, 0.0f, 0.0f);
    }
}

// ---------------------------------------------------------------------- host
extern "C" void kernel_launch(void* const* d_in, const int* in_sizes, int n_in,
                              void* d_out, int out_size, void* d_ws, size_t ws_size,
                              hipStream_t stream)
{
    const float* x   = (const float*)d_in[0];
    const float* Ws1 = (const float*)d_in[1];
    const float* bs1 = (const float*)d_in[2];
    const float* Ws2 = (const float*)d_in[3];
    const float* bs2 = (const float*)d_in[4];
    const float* Wp1 = (const float*)d_in[5];
    const float* bp1 = (const float*)d_in[6];
    const float* Wp2 = (const float*)d_in[7];
    const float* bp2 = (const float*)d_in[8];
    const int* esrc  = (const int*)d_in[9];
    const int* edst  = (const int*)d_in[10];

    int E = in_sizes[9];
    int N = in_sizes[0] / DIM;
    int G = N / NPG;

    float* score = (float*)d_ws;                               // N floats
    float* gate  = score + N;                                  // N floats
    int* counts  = (int*)(gate + N);                           // G ints
    int* keep    = counts + G;                                 // G ints

    float* out_x    = (float*)d_out;
    float* out_mask = out_x + (size_t)N * DIM;

    hipMemsetAsync(counts, 0, G * sizeof(int), stream);
    k_score<<<(N + 127) / 128, 256, 0, stream>>>(x, Ws1, bs1, Ws2, bs2, score, N);
    k_edges<<<512, 256, 0, stream>>>(esrc, edst, counts, E, G);
    k_keep<<<G, 256, 0, stream>>>(score, counts, Wp1, bp1, Wp2, bp2, keep);
    k_rank<<<G, 256, 0, stream>>>(score, keep, out_mask, gate);
    k_write<<<(N + 3) / 4, 256, 0, stream>>>(x, gate, out_x, N);
}

// Round 6
// 145.920 us; speedup vs baseline: 2.0900x; 2.0900x over previous
//
#include <hip/hip_runtime.h>
#include <math.h>

#define NPG 500      // nodes per graph
#define DIM 256      // feature dim
#define HID 64       // hidden dim
#define RATIO_NORM 600.0f

// ---------------------------------------------------------------- K1: scores
// score[n] = relu(x[n,:] @ Ws1 + bs1) @ Ws2 + bs2
// Weights staged in LDS (64KB, whole Ws1) by the block; inner loop reads them
// as same-address broadcast ds_read_b128 (conflict-free, ~free) -> no scalar
// MSHR cap, no global latency on the critical path. 512 thr = 8 waves:
// wave = (node_half, h_slice16); each lane owns 2 nodes. 256 nodes/block.
__global__ __launch_bounds__(512, 4) void k_score(
    const float* __restrict__ x,
    const float* __restrict__ Ws1,   // [DIM][HID] row-major
    const float* __restrict__ bs1,   // [HID]
    const float* __restrict__ Ws2,   // [HID]
    const float* __restrict__ bs2,   // [1]
    float* __restrict__ score, int N)
{
    __shared__ float w_lds[DIM * HID];   // 64 KB (reused for reduction later)

    int tid = threadIdx.x;
    // cooperative stage of Ws1: 4096 float4 / 512 threads = 8 per thread
    {
        const float4* src = reinterpret_cast<const float4*>(Ws1);
        float4* dst = reinterpret_cast<float4*>(w_lds);
        for (int i = tid; i < DIM * HID / 4; i += 512) dst[i] = src[i];
    }
    __syncthreads();

    int lane = tid & 63;
    int wv   = tid >> 6;        // 0..7
    int half = wv >> 2;         // node half: 0 or 1
    int hs   = wv & 3;          // h-slice id
    int h0   = hs * 16;
    int nbase = blockIdx.x * 256 + half * 128;
    int n0 = nbase + lane;
    int n1 = nbase + 64 + lane;
    int n0c = n0 < N ? n0 : (N - 1);
    int n1c = n1 < N ? n1 : (N - 1);

    const float4* xr0 = reinterpret_cast<const float4*>(x + (size_t)n0c * DIM);
    const float4* xr1 = reinterpret_cast<const float4*>(x + (size_t)n1c * DIM);
    const float* bs = bs1 + h0;

    float4 A[4], B[4];
#pragma unroll
    for (int j = 0; j < 4; ++j) {
        A[j] = *reinterpret_cast<const float4*>(bs + j * 4);
        B[j] = A[j];
    }

    // 3-deep x prefetch (L3 latency ~700cy)
    float4 xa0 = xr0[0], xa1 = xr0[1], xa2 = xr0[2];
    float4 xb0 = xr1[0], xb1 = xr1[1], xb2 = xr1[2];

    for (int k4 = 0; k4 < DIM / 4; ++k4) {
        const float* wb = w_lds + (size_t)(k4 * 4) * HID + h0;
#pragma unroll
        for (int kk = 0; kk < 4; ++kk) {
            float4 w0 = *reinterpret_cast<const float4*>(wb + kk * HID);
            float4 w1 = *reinterpret_cast<const float4*>(wb + kk * HID + 4);
            float4 w2 = *reinterpret_cast<const float4*>(wb + kk * HID + 8);
            float4 w3 = *reinterpret_cast<const float4*>(wb + kk * HID + 12);
            float xk0 = kk == 0 ? xa0.x : kk == 1 ? xa0.y : kk == 2 ? xa0.z : xa0.w;
            float xk1 = kk == 0 ? xb0.x : kk == 1 ? xb0.y : kk == 2 ? xb0.z : xb0.w;
            A[0].x = fmaf(xk0, w0.x, A[0].x);  B[0].x = fmaf(xk1, w0.x, B[0].x);
            A[0].y = fmaf(xk0, w0.y, A[0].y);  B[0].y = fmaf(xk1, w0.y, B[0].y);
            A[0].z = fmaf(xk0, w0.z, A[0].z);  B[0].z = fmaf(xk1, w0.z, B[0].z);
            A[0].w = fmaf(xk0, w0.w, A[0].w);  B[0].w = fmaf(xk1, w0.w, B[0].w);
            A[1].x = fmaf(xk0, w1.x, A[1].x);  B[1].x = fmaf(xk1, w1.x, B[1].x);
            A[1].y = fmaf(xk0, w1.y, A[1].y);  B[1].y = fmaf(xk1, w1.y, B[1].y);
            A[1].z = fmaf(xk0, w1.z, A[1].z);  B[1].z = fmaf(xk1, w1.z, B[1].z);
            A[1].w = fmaf(xk0, w1.w, A[1].w);  B[1].w = fmaf(xk1, w1.w, B[1].w);
            A[2].x = fmaf(xk0, w2.x, A[2].x);  B[2].x = fmaf(xk1, w2.x, B[2].x);
            A[2].y = fmaf(xk0, w2.y, A[2].y);  B[2].y = fmaf(xk1, w2.y, B[2].y);
            A[2].z = fmaf(xk0, w2.z, A[2].z);  B[2].z = fmaf(xk1, w2.z, B[2].z);
            A[2].w = fmaf(xk0, w2.w, A[2].w);  B[2].w = fmaf(xk1, w2.w, B[2].w);
            A[3].x = fmaf(xk0, w3.x, A[3].x);  B[3].x = fmaf(xk1, w3.x, B[3].x);
            A[3].y = fmaf(xk0, w3.y, A[3].y);  B[3].y = fmaf(xk1, w3.y, B[3].y);
            A[3].z = fmaf(xk0, w3.z, A[3].z);  B[3].z = fmaf(xk1, w3.z, B[3].z);
            A[3].w = fmaf(xk0, w3.w, A[3].w);  B[3].w = fmaf(xk1, w3.w, B[3].w);
        }
        int ix = k4 + 3 < DIM / 4 ? k4 + 3 : DIM / 4 - 1;
        xa0 = xa1; xa1 = xa2; xa2 = xr0[ix];
        xb0 = xb1; xb1 = xb2; xb2 = xr1[ix];
    }

    // second layer partial on this wave's 16 h
    float4 w20 = *reinterpret_cast<const float4*>(Ws2 + h0);
    float4 w21 = *reinterpret_cast<const float4*>(Ws2 + h0 + 4);
    float4 w22 = *reinterpret_cast<const float4*>(Ws2 + h0 + 8);
    float4 w23 = *reinterpret_cast<const float4*>(Ws2 + h0 + 12);
    float p0 = 0.0f, p1 = 0.0f;
    p0 = fmaf(fmaxf(A[0].x, 0.0f), w20.x, p0);  p1 = fmaf(fmaxf(B[0].x, 0.0f), w20.x, p1);
    p0 = fmaf(fmaxf(A[0].y, 0.0f), w20.y, p0);  p1 = fmaf(fmaxf(B[0].y, 0.0f), w20.y, p1);
    p0 = fmaf(fmaxf(A[0].z, 0.0f), w20.z, p0);  p1 = fmaf(fmaxf(B[0].z, 0.0f), w20.z, p1);
    p0 = fmaf(fmaxf(A[0].w, 0.0f), w20.w, p0);  p1 = fmaf(fmaxf(B[0].w, 0.0f), w20.w, p1);
    p0 = fmaf(fmaxf(A[1].x, 0.0f), w21.x, p0);  p1 = fmaf(fmaxf(B[1].x, 0.0f), w21.x, p1);
    p0 = fmaf(fmaxf(A[1].y, 0.0f), w21.y, p0);  p1 = fmaf(fmaxf(B[1].y, 0.0f), w21.y, p1);
    p0 = fmaf(fmaxf(A[1].z, 0.0f), w21.z, p0);  p1 = fmaf(fmaxf(B[1].z, 0.0f), w21.z, p1);
    p0 = fmaf(fmaxf(A[1].w, 0.0f), w21.w, p0);  p1 = fmaf(fmaxf(B[1].w, 0.0f), w21.w, p1);
    p0 = fmaf(fmaxf(A[2].x, 0.0f), w22.x, p0);  p1 = fmaf(fmaxf(B[2].x, 0.0f), w22.x, p1);
    p0 = fmaf(fmaxf(A[2].y, 0.0f), w22.y, p0);  p1 = fmaf(fmaxf(B[2].y, 0.0f), w22.y, p1);
    p0 = fmaf(fmaxf(A[2].z, 0.0f), w22.z, p0);  p1 = fmaf(fmaxf(B[2].z, 0.0f), w22.z, p1);
    p0 = fmaf(fmaxf(A[2].w, 0.0f), w22.w, p0);  p1 = fmaf(fmaxf(B[2].w, 0.0f), w22.w, p1);
    p0 = fmaf(fmaxf(A[3].x, 0.0f), w23.x, p0);  p1 = fmaf(fmaxf(B[3].x, 0.0f), w23.x, p1);
    p0 = fmaf(fmaxf(A[3].y, 0.0f), w23.y, p0);  p1 = fmaf(fmaxf(B[3].y, 0.0f), w23.y, p1);
    p0 = fmaf(fmaxf(A[3].z, 0.0f), w23.z, p0);  p1 = fmaf(fmaxf(B[3].z, 0.0f), w23.z, p1);
    p0 = fmaf(fmaxf(A[3].w, 0.0f), w23.w, p0);  p1 = fmaf(fmaxf(B[3].w, 0.0f), w23.w, p1);

    // reduce across 4 h-slices; reuse w_lds as part[hs][256]
    __syncthreads();                       // everyone done reading weights
    float* part = w_lds;
    part[hs * 256 + half * 128 + lane] = p0;
    part[hs * 256 + half * 128 + 64 + lane] = p1;
    __syncthreads();
    if (tid < 256) {
        float s = part[tid] + part[256 + tid] + part[512 + tid] + part[768 + tid]
                + bs2[0];
        int node = blockIdx.x * 256 + tid;
        if (node < N) score[node] = s;
    }
}

// ------------------------------------------------------------- K2: edge count
__global__ __launch_bounds__(256) void k_edges(
    const int* __restrict__ esrc, const int* __restrict__ edst,
    int* __restrict__ counts, int E, int G)
{
    __shared__ int hist[256];
    for (int i = threadIdx.x; i < G; i += 256) hist[i] = 0;
    __syncthreads();

    int nchunk = E >> 2;
    const int4* s4 = reinterpret_cast<const int4*>(esrc);
    const int4* d4 = reinterpret_cast<const int4*>(edst);
    for (int c = blockIdx.x * 256 + threadIdx.x; c < nchunk; c += gridDim.x * 256) {
        int4 s = s4[c], d = d4[c];
        int g;
        g = s.x / NPG; if (g == d.x / NPG) atomicAdd(&hist[g], 1);
        g = s.y / NPG; if (g == d.y / NPG) atomicAdd(&hist[g], 1);
        g = s.z / NPG; if (g == d.z / NPG) atomicAdd(&hist[g], 1);
        g = s.w / NPG; if (g == d.w / NPG) atomicAdd(&hist[g], 1);
    }
    if (blockIdx.x == 0) {
        for (int e = (nchunk << 2) + threadIdx.x; e < E; e += 256) {
            int g = esrc[e] / NPG;
            if (g == edst[e] / NPG) atomicAdd(&hist[g], 1);
        }
    }
    __syncthreads();
    for (int i = threadIdx.x; i < G; i += 256)
        if (hist[i]) atomicAdd(&counts[i], hist[i]);
}

// ------------------------------------------- K3: per-graph avg + keep_num MLP
__global__ __launch_bounds__(256) void k_keep(
    const float* __restrict__ score,
    const int* __restrict__ counts,
    const float* __restrict__ Wp1,   // [3][HID]
    const float* __restrict__ bp1,   // [HID]
    const float* __restrict__ Wp2,   // [HID]
    const float* __restrict__ bp2,   // [1]
    int* __restrict__ keep_num)
{
    int g = blockIdx.x;
    __shared__ float red[256];
    const float* s = score + (size_t)g * NPG;
    float v = 0.0f;
    for (int i = threadIdx.x; i < NPG; i += 256) v += s[i];
    red[threadIdx.x] = v;
    __syncthreads();
    for (int off = 128; off >= 1; off >>= 1) {
        if (threadIdx.x < off) red[threadIdx.x] += red[threadIdx.x + off];
        __syncthreads();
    }
    if (threadIdx.x < 64) {
        float f0 = (float)NPG / RATIO_NORM;
        float f1 = red[0] / (float)NPG;
        float f2 = (float)counts[g] / (float)(NPG * (NPG - 1));
        int h = threadIdx.x;
        float hv = bp1[h];
        hv = fmaf(f0, Wp1[h], hv);
        hv = fmaf(f1, Wp1[HID + h], hv);
        hv = fmaf(f2, Wp1[2 * HID + h], hv);
        hv = fmaxf(hv, 0.0f) * Wp2[h];
#pragma unroll
        for (int m = 32; m >= 1; m >>= 1) hv += __shfl_xor(hv, m, 64);
        if (h == 0) {
            float z = hv + bp2[0];
            float kr = 1.0f / (1.0f + expf(-z));
            int kn = (int)((float)NPG * kr);
            keep_num[g] = kn < 2 ? 2 : kn;
        }
    }
}

// ---------------------------- K4a: per-graph rank -> mask (float) + gate tanh
__global__ __launch_bounds__(256) void k_rank(
    const float* __restrict__ score,
    const int* __restrict__ keep_num,
    float* __restrict__ out_mask,   // [N] 0.0/1.0
    float* __restrict__ gate)       // [N] tanh(score) or 0
{
    int g = blockIdx.x;
    __shared__ float s[NPG];
    const float* sg = score + (size_t)g * NPG;
    for (int i = threadIdx.x; i < NPG; i += 256) s[i] = sg[i];
    __syncthreads();

    int kn = keep_num[g];
    for (int i = threadIdx.x; i < NPG; i += 256) {
        float si = s[i];
        int rank = 0;
        for (int j = 0; j < NPG; ++j) {
            float sj = s[j];
            rank += (sj > si) || ((sj == si) && (j < i));
        }
        bool keep = rank < kn;
        size_t idx = (size_t)g * NPG + i;
        out_mask[idx] = keep ? 1.0f : 0.0f;
        gate[idx] = keep ? tanhf(si) : 0.0f;
    }
}

// ------------------------------------------ K4b: gated row write (full BW)
__global__ __launch_bounds__(256) void k_write(
    const float* __restrict__ x,
    const float* __restrict__ gate,
    float* __restrict__ out_x, int N)
{
    int lane = threadIdx.x & 63;
    int row = blockIdx.x * 4 + (threadIdx.x >> 6);
    if (row >= N) return;
    float gt = gate[row];
    size_t base = (size_t)row * DIM;
    float4* o = reinterpret_cast<float4*>(out_x + base);
    if (gt != 0.0f) {
        const float4* xi = reinterpret_cast<const float4*>(x + base);
        float4 v = xi[lane];
        o[lane] = make_float4(v.x * gt, v.y * gt, v.z * gt, v.w * gt);
    } else {
        o[lane] = make_float4(0.0f, 0.0f, 0.0f, 0.0f);
    }
}

// ---------------------------------------------------------------------- host
extern "C" void kernel_launch(void* const* d_in, const int* in_sizes, int n_in,
                              void* d_out, int out_size, void* d_ws, size_t ws_size,
                              hipStream_t stream)
{
    const float* x   = (const float*)d_in[0];
    const float* Ws1 = (const float*)d_in[1];
    const float* bs1 = (const float*)d_in[2];
    const float* Ws2 = (const float*)d_in[3];
    const float* bs2 = (const float*)d_in[4];
    const float* Wp1 = (const float*)d_in[5];
    const float* bp1 = (const float*)d_in[6];
    const float* Wp2 = (const float*)d_in[7];
    const float* bp2 = (const float*)d_in[8];
    const int* esrc  = (const int*)d_in[9];
    const int* edst  = (const int*)d_in[10];

    int E = in_sizes[9];
    int N = in_sizes[0] / DIM;
    int G = N / NPG;

    float* score = (float*)d_ws;                               // N floats
    float* gate  = score + N;                                  // N floats
    int* counts  = (int*)(gate + N);                           // G ints
    int* keep    = counts + G;                                 // G ints

    float* out_x    = (float*)d_out;
    float* out_mask = out_x + (size_t)N * DIM;

    hipMemsetAsync(counts, 0, G * sizeof(int), stream);
    k_score<<<(N + 255) / 256, 512, 0, stream>>>(x, Ws1, bs1, Ws2, bs2, score, N);
    k_edges<<<512, 256, 0, stream>>>(esrc, edst, counts, E, G);
    k_keep<<<G, 256, 0, stream>>>(score, counts, Wp1, bp1, Wp2, bp2, keep);
    k_rank<<<G, 256, 0, stream>>>(score, keep, out_mask, gate);
    k_write<<<(N + 3) / 4, 256, 0, stream>>>(x, gate, out_x, N);
}